// Round 9
// baseline (2304.948 us; speedup 1.0000x reference)
//
#include <hip/hip_runtime.h>

// Chebyshev GCN: out = sum_k S_k @ X @ W_k + bias.
// Pipeline (all per-support segments fused when ws allows):
//  1. hist_bins:   per-(support,bin) edge counts (bin = row>>7), LDS-staged.
//  2. scanA/B/C:   exclusive scan of the 3*NBINS counts -> offs (+cursor copy).
//  3. reorder_bins: block-range ticketing — each 16K-edge block reserves ONE
//     contiguous range per bin (single global atomic per (block,bin)), then
//     writes block-private chunks. Lines have a single-XCD writer -> kills the
//     8x partial-line write amplification measured in round 6 (299MB->~50MB).
//  4. spmm_bins:   one block per bin of 128 rows. 32KB LDS f32 accumulator.
//     Edge list per (k,bin) is contiguous -> full-efficiency 64-wide batched
//     packed load + readlane broadcast + ds_add_f32 (fire-and-forget).
//     Output kept in registers across the 3 supports; epilogue applies W_k via
//     readlane x W-column-in-VGPR; single out write (+bias).

#define ROWS_PER_BIN 128
#define MAX_BINS 1024
#define HIST_EDGES 4096
#define REORD_EDGES 16384

__global__ __launch_bounds__(256) void zero_kernel(int* __restrict__ p, int n) {
  int i = blockIdx.x * 256 + threadIdx.x;
  if (i < n) p[i] = 0;
}

// grid: nsup*EB blocks (k = blockIdx.x/EB); LDS histogram then one global
// (non-returning) atomic per non-empty bin.
__global__ __launch_bounds__(256) void hist_bins_kernel(
    const int* __restrict__ rows, int* __restrict__ totals,
    int E, int EB, int NBINS) {
  __shared__ int lh[MAX_BINS];
  const int k = blockIdx.x / EB;
  const int eb = blockIdx.x % EB;
  for (int b = threadIdx.x; b < NBINS; b += 256) lh[b] = 0;
  __syncthreads();
  const int s = eb * HIST_EDGES, e = min(E, s + HIST_EDGES);
  const size_t kE = (size_t)k * E;
  for (int i = s + threadIdx.x; i < e; i += 256)
    atomicAdd(&lh[rows[kE + i] >> 7], 1);
  __syncthreads();
  for (int b = threadIdx.x; b < NBINS; b += 256) {
    int c = lh[b];
    if (c) atomicAdd(&totals[k * NBINS + b], c);
  }
}

// per-block (2048 elems) sum -> blockSums
__global__ __launch_bounds__(512) void scanA_kernel(
    const int* __restrict__ counts, int* __restrict__ blockSums, int M) {
  __shared__ int wsum[8];
  const int t = threadIdx.x;
  const int i0 = blockIdx.x * 2048 + t * 4;
  int s = 0;
  if (i0 + 3 < M) {
    int4 c = *reinterpret_cast<const int4*>(counts + i0);
    s = c.x + c.y + c.z + c.w;
  } else {
#pragma unroll
    for (int u = 0; u < 4; ++u)
      if (i0 + u < M) s += counts[i0 + u];
  }
#pragma unroll
  for (int off = 32; off; off >>= 1) s += __shfl_down(s, off);
  if ((t & 63) == 0) wsum[t >> 6] = s;
  __syncthreads();
  if (t == 0) {
    int tot = 0;
#pragma unroll
    for (int w = 0; w < 8; ++w) tot += wsum[w];
    blockSums[blockIdx.x] = tot;
  }
}

// exclusive scan of blockSums[NB], NB <= 256, one block
__global__ __launch_bounds__(256) void scanB_kernel(int* __restrict__ bs, int NB) {
  __shared__ int s[2][256];
  int t = threadIdx.x;
  int v = (t < NB) ? bs[t] : 0;
  s[0][t] = v;
  __syncthreads();
  int cur = 0;
  for (int off = 1; off < 256; off <<= 1) {
    int nv = s[cur][t] + ((t >= off) ? s[cur][t - off] : 0);
    s[cur ^ 1][t] = nv;
    cur ^= 1;
    __syncthreads();
  }
  if (t < NB) bs[t] = s[cur][t] - v;
}

// full exclusive scan -> offsets, cursor
__global__ __launch_bounds__(512) void scanC_kernel(
    const int* __restrict__ counts, const int* __restrict__ bs,
    int* __restrict__ offsets, int* __restrict__ cursor, int M) {
  __shared__ int wsum[8];
  const int t = threadIdx.x;
  const int lane = t & 63;
  const int wid = t >> 6;
  const int i0 = blockIdx.x * 2048 + t * 4;
  int c0 = 0, c1 = 0, c2 = 0, c3 = 0;
  if (i0 + 3 < M) {
    int4 c = *reinterpret_cast<const int4*>(counts + i0);
    c0 = c.x; c1 = c.y; c2 = c.z; c3 = c.w;
  } else {
    if (i0 + 0 < M) c0 = counts[i0 + 0];
    if (i0 + 1 < M) c1 = counts[i0 + 1];
    if (i0 + 2 < M) c2 = counts[i0 + 2];
  }
  int s = c0 + c1 + c2 + c3;
  int inc = s;
#pragma unroll
  for (int off = 1; off < 64; off <<= 1) {
    int v = __shfl_up(inc, off);
    if (lane >= off) inc += v;
  }
  if (lane == 63) wsum[wid] = inc;
  __syncthreads();
  int wbase = 0;
#pragma unroll
  for (int w = 0; w < 8; ++w) wbase += (w < wid) ? wsum[w] : 0;
  int excl = bs[blockIdx.x] + wbase + (inc - s);
  int o0 = excl, o1 = o0 + c0, o2 = o1 + c1, o3 = o2 + c2;
  if (i0 + 0 < M) { offsets[i0 + 0] = o0; cursor[i0 + 0] = o0; }
  if (i0 + 1 < M) { offsets[i0 + 1] = o1; cursor[i0 + 1] = o1; }
  if (i0 + 2 < M) { offsets[i0 + 2] = o2; cursor[i0 + 2] = o2; }
  if (i0 + 3 < M) { offsets[i0 + 3] = o3; cursor[i0 + 3] = o3; }
}

// Block-range ticketed binning. pack: p.x = col | (local_row<<25), p.y = val.
__global__ __launch_bounds__(256) void reorder_bins_kernel(
    const int* __restrict__ rows, const int* __restrict__ cols,
    const float* __restrict__ vals, int* __restrict__ cursor,
    int2* __restrict__ packed, int E, int EB, int NBINS) {
  __shared__ int lh[MAX_BINS];
  __shared__ int lbase[MAX_BINS];
  const int k = blockIdx.x / EB;
  const int eb = blockIdx.x % EB;
  for (int b = threadIdx.x; b < NBINS; b += 256) lh[b] = 0;
  __syncthreads();
  const int s = eb * REORD_EDGES, e = min(E, s + REORD_EDGES);
  const size_t kE = (size_t)k * E;
  // pass 1: count this block's edges per bin
  for (int i = s + threadIdx.x; i < e; i += 256)
    atomicAdd(&lh[rows[kE + i] >> 7], 1);
  __syncthreads();
  // pass 2: reserve one contiguous range per non-empty bin
  for (int b = threadIdx.x; b < NBINS; b += 256) {
    int c = lh[b];
    lbase[b] = c ? atomicAdd(&cursor[k * NBINS + b], c) : 0;
  }
  __syncthreads();
  for (int b = threadIdx.x; b < NBINS; b += 256) lh[b] = 0;
  __syncthreads();
  // pass 3: place edges at block-private positions
  for (int i = s + threadIdx.x; i < e; i += 256) {
    int r = rows[kE + i];
    int bin = r >> 7, lr = r & 127;
    int lp = atomicAdd(&lh[bin], 1);
    packed[lbase[bin] + lp] =
        make_int2(cols[kE + i] | (lr << 25), __float_as_int(vals[kE + i]));
  }
}

// One block per bin of 128 rows; LDS f32 accumulator; register out-accum
// across supports; epilogue readlane x W-column-in-VGPR.
__global__ __launch_bounds__(256) void spmm_bins_kernel(
    const int2* __restrict__ packed, const int* __restrict__ offs,
    const float* __restrict__ X, const float* __restrict__ W,
    const float* __restrict__ bias, float* __restrict__ out,
    int N, int NBINS, int kFirst, int kCount, int totalE) {
  __shared__ float acc[ROWS_PER_BIN * 64];  // 32 KB
  const int bin = blockIdx.x;
  const int lane = threadIdx.x & 63;
  const int wid = threadIdx.x >> 6;  // 4 waves; wave owns rows [wid*32, wid*32+32)
  float oacc[32];
#pragma unroll
  for (int i = 0; i < 32; ++i) oacc[i] = 0.f;

  for (int kl = 0; kl < kCount; ++kl) {
    for (int idx = threadIdx.x; idx < ROWS_PER_BIN * 64; idx += 256)
      acc[idx] = 0.f;
    __syncthreads();
    const int segIdx = kl * NBINS + bin;
    const int s = offs[segIdx];
    const int e = (segIdx + 1 < kCount * NBINS) ? offs[segIdx + 1] : totalE;
    for (int b2 = s + wid * 64; b2 < e; b2 += 256) {
      int2 p = packed[b2 + lane];  // buffer padded by 64 entries
      const int lim = min(64, e - b2);
      int j = 0;
      for (; j + 3 < lim; j += 4) {
        unsigned q0 = (unsigned)__builtin_amdgcn_readlane(p.x, j + 0);
        unsigned q1 = (unsigned)__builtin_amdgcn_readlane(p.x, j + 1);
        unsigned q2 = (unsigned)__builtin_amdgcn_readlane(p.x, j + 2);
        unsigned q3 = (unsigned)__builtin_amdgcn_readlane(p.x, j + 3);
        float v0 = __int_as_float(__builtin_amdgcn_readlane(p.y, j + 0));
        float v1 = __int_as_float(__builtin_amdgcn_readlane(p.y, j + 1));
        float v2 = __int_as_float(__builtin_amdgcn_readlane(p.y, j + 2));
        float v3 = __int_as_float(__builtin_amdgcn_readlane(p.y, j + 3));
        float x0 = X[(size_t)(q0 & 0x1FFFFFFu) * 64 + lane];
        float x1 = X[(size_t)(q1 & 0x1FFFFFFu) * 64 + lane];
        float x2 = X[(size_t)(q2 & 0x1FFFFFFu) * 64 + lane];
        float x3 = X[(size_t)(q3 & 0x1FFFFFFu) * 64 + lane];
        atomicAdd(&acc[(q0 >> 25) * 64 + lane], v0 * x0);
        atomicAdd(&acc[(q1 >> 25) * 64 + lane], v1 * x1);
        atomicAdd(&acc[(q2 >> 25) * 64 + lane], v2 * x2);
        atomicAdd(&acc[(q3 >> 25) * 64 + lane], v3 * x3);
      }
      for (; j < lim; ++j) {
        unsigned q = (unsigned)__builtin_amdgcn_readlane(p.x, j);
        float v = __int_as_float(__builtin_amdgcn_readlane(p.y, j));
        float x = X[(size_t)(q & 0x1FFFFFFu) * 64 + lane];
        atomicAdd(&acc[(q >> 25) * 64 + lane], v * x);
      }
    }
    __syncthreads();
    // epilogue: oacc[row] += acc[row,:] @ W_kk
    const int kk = kFirst + kl;
    float wv[64];
#pragma unroll
    for (int i = 0; i < 64; ++i) wv[i] = W[((size_t)kk * 64 + i) * 64 + lane];
#pragma unroll
    for (int i = 0; i < 32; ++i) {
      const int lr = wid * 32 + i;
      const int row = bin * ROWS_PER_BIN + lr;
      if (row < N) {
        int ai = __float_as_int(acc[lr * 64 + lane]);
        float p0 = 0.f, p1 = 0.f, p2 = 0.f, p3 = 0.f;
#pragma unroll
        for (int m = 0; m < 16; ++m) {
          p0 = fmaf(__int_as_float(__builtin_amdgcn_readlane(ai, 4 * m + 0)), wv[4 * m + 0], p0);
          p1 = fmaf(__int_as_float(__builtin_amdgcn_readlane(ai, 4 * m + 1)), wv[4 * m + 1], p1);
          p2 = fmaf(__int_as_float(__builtin_amdgcn_readlane(ai, 4 * m + 2)), wv[4 * m + 2], p2);
          p3 = fmaf(__int_as_float(__builtin_amdgcn_readlane(ai, 4 * m + 3)), wv[4 * m + 3], p3);
        }
        oacc[i] += (p0 + p1) + (p2 + p3);
      }
    }
    __syncthreads();
  }
#pragma unroll
  for (int i = 0; i < 32; ++i) {
    const int lr = wid * 32 + i;
    const int row = bin * ROWS_PER_BIN + lr;
    if (row < N) {
      float v = oacc[i];
      v += (kFirst == 0) ? bias[lane] : out[(size_t)row * 64 + lane];
      out[(size_t)row * 64 + lane] = v;
    }
  }
}

extern "C" void kernel_launch(void* const* d_in, const int* in_sizes, int n_in,
                              void* d_out, int out_size, void* d_ws, size_t ws_size,
                              hipStream_t stream) {
  const float* X    = (const float*)d_in[0];  // [N, 64]
  const int*   rows = (const int*)d_in[1];    // [3, E]
  const int*   cols = (const int*)d_in[2];    // [3, E]
  const float* vals = (const float*)d_in[3];  // [3, E]
  const float* W    = (const float*)d_in[4];  // [192, 64]
  const float* bias = (const float*)d_in[5];  // [64]
  float* out = (float*)d_out;                 // [N, 64] f32

  const int N = in_sizes[0] / 64;
  const int E = in_sizes[1] / 3;
  const int NBINS = (N + ROWS_PER_BIN - 1) / ROWS_PER_BIN;  // 782; <= MAX_BINS
  const int EBh = (E + HIST_EDGES - 1) / HIST_EDGES;
  const int EBr = (E + REORD_EDGES - 1) / REORD_EDGES;

  const size_t needFused =
      ((size_t)3 * E + 64) * 8 + 3 * ((size_t)3 * NBINS * 4) + 2048;
  const bool fused = ws_size >= needFused;
  const int nsup = fused ? 3 : 1;
  const int M = nsup * NBINS;

  char* wp = (char*)d_ws;
  int2* packed   = (int2*)wp;  wp += ((size_t)nsup * E + 64) * 8;
  int* totals    = (int*)wp;   wp += (size_t)M * 4;
  int* offs      = (int*)wp;   wp += (size_t)M * 4;
  int* cursor    = (int*)wp;   wp += (size_t)M * 4;
  int* blockSums = (int*)wp;

  const int NB = (M + 2047) / 2048;  // <= 2
  const int zB = (M + 255) / 256;

  if (fused) {
    zero_kernel<<<zB, 256, 0, stream>>>(totals, M);
    hist_bins_kernel<<<3 * EBh, 256, 0, stream>>>(rows, totals, E, EBh, NBINS);
    scanA_kernel<<<NB, 512, 0, stream>>>(totals, blockSums, M);
    scanB_kernel<<<1, 256, 0, stream>>>(blockSums, NB);
    scanC_kernel<<<NB, 512, 0, stream>>>(totals, blockSums, offs, cursor, M);
    reorder_bins_kernel<<<3 * EBr, 256, 0, stream>>>(
        rows, cols, vals, cursor, packed, E, EBr, NBINS);
    spmm_bins_kernel<<<NBINS, 256, 0, stream>>>(
        packed, offs, X, W, bias, out, N, NBINS, 0, 3, 3 * E);
  } else {
    for (int k = 0; k < 3; ++k) {
      zero_kernel<<<zB, 256, 0, stream>>>(totals, M);
      hist_bins_kernel<<<EBh, 256, 0, stream>>>(
          rows + (size_t)k * E, totals, E, EBh, NBINS);
      scanA_kernel<<<NB, 512, 0, stream>>>(totals, blockSums, M);
      scanB_kernel<<<1, 256, 0, stream>>>(blockSums, NB);
      scanC_kernel<<<NB, 512, 0, stream>>>(totals, blockSums, offs, cursor, M);
      reorder_bins_kernel<<<EBr, 256, 0, stream>>>(
          rows + (size_t)k * E, cols + (size_t)k * E, vals + (size_t)k * E,
          cursor, packed, E, EBr, NBINS);
      spmm_bins_kernel<<<NBINS, 256, 0, stream>>>(
          packed, offs, X, W, bias, out, N, NBINS, k, 1, E);
    }
  }
}